// Round 19
// baseline (6821.112 us; speedup 1.0000x reference)
//
#include <hip/hip_runtime.h>
#include <hip/hip_bf16.h>

// ---------------------------------------------------------------------------
// 2-layer LSTM, B=32, T=512, H=1024, fp32 in/out.
// Round 19 (base = r18, 5.61ms, absmax 0.0547):
//   4-WAY K-SPLIT: quad (wg&~3) shares 16 units (64 gate cols); member
//   q=wg&3 covers K in [q*256,+256). Per-CU consume halves again
//   (160->80 KB/step; calibrated slope 64KB <-> 1.78us). Exchange: each wg
//   UC-publishes its full partial psum (16KB), polls 3 quadmate flags,
//   reads 3x4KB slices (its epilogue cols) and adds. Slot-reuse safety =
//   r18 proof (pex(s+1) writes gated by global arrival barrier of s).
//   Epilogued unit = (wg>>2)*16+(wg&3)*4+ca == wg*4+ca -> epilogue/publish/
//   hp/staging/barriers byte-identical to r18. Same FLOPs.
// ---------------------------------------------------------------------------

constexpr int Hh = 1024;
constexpr int Bb = 32;
constexpr int Tt = 512;
constexpr int NUG = 64;                // unit groups (16 units each)
constexpr int PLE  = 32 * 1024;        // elems per staged plane [32][1024]
constexpr int ST3E = 3 * PLE;          // 3 planes per staged slot

typedef float f32x4 __attribute__((ext_vector_type(4)));
typedef int   i32x4 __attribute__((ext_vector_type(4)));

__device__ inline void mfma_bf16(f32x4& acc, i32x4 a, i32x4 b) {
    asm("s_nop 2\n\tv_mfma_f32_16x16x32_bf16 %0, %1, %2, %0"
        : "+v"(acc) : "v"(a), "v"(b));
}

__device__ inline i32x4 uload_x4(const void* p) {
    i32x4 r;
    asm volatile("global_load_dwordx4 %0, %1, off sc0 sc1\n\ts_waitcnt vmcnt(0)"
                 : "=&v"(r) : "v"(p) : "memory");
    return r;
}
__device__ inline void ustore_x4(void* p, i32x4 v) {
    asm volatile("global_store_dwordx4 %0, %1, off sc0 sc1"
                 :: "v"(p), "v"(v) : "memory");
}
__device__ inline i32x4 pload_x4(const unsigned short* p) {  // plain cached
    return *(const i32x4*)p;
}
__device__ inline void astore_u32(unsigned int* p, unsigned v) {
    __hip_atomic_store(p, v, __ATOMIC_RELAXED, __HIP_MEMORY_SCOPE_AGENT);
}
__device__ inline unsigned aload_u32(const unsigned int* p) {
    return __hip_atomic_load(p, __ATOMIC_RELAXED, __HIP_MEMORY_SCOPE_AGENT);
}

__device__ inline unsigned short f2bf(float f) {
    unsigned u = __float_as_uint(f);
    u += 0x7fffu + ((u >> 16) & 1u);
    return (unsigned short)(u >> 16);
}
__device__ inline float bf2f(unsigned short s) {
    return __uint_as_float((unsigned)s << 16);
}

__device__ inline float sigm(float x)  { return 1.f / (1.f + __expf(-x)); }
__device__ inline float tanh_f(float x){ return 1.f - 2.f / (__expf(2.f * x) + 1.f); }

// x [32][512][1024] f32 -> xT hi/lo [513][32][1024] bf16 (slot 512 zeroed)
__global__ __launch_bounds__(256) void k_xT(const float* __restrict__ x,
                                            unsigned short* __restrict__ xh,
                                            unsigned short* __restrict__ xl,
                                            int use_lo) {
    int bid = blockIdx.x;               // 0..16415
    int t = bid >> 5, b = bid & 31;
    size_t o = ((size_t)t * Bb + b) * Hh;
    if (t == Tt) {
        ushort4 z = {0, 0, 0, 0};
        ((ushort4*)(xh + o))[threadIdx.x] = z;
        if (use_lo) ((ushort4*)(xl + o))[threadIdx.x] = z;
        return;
    }
    const float4* src = (const float4*)(x + ((size_t)b * Tt + t) * Hh);
    float4 v = src[threadIdx.x];
    ushort4 hi;
    hi.x = f2bf(v.x); hi.y = f2bf(v.y); hi.z = f2bf(v.z); hi.w = f2bf(v.w);
    ((ushort4*)(xh + o))[threadIdx.x] = hi;
    if (use_lo) {
        ushort4 lo;
        lo.x = f2bf(v.x - bf2f(hi.x));
        lo.y = f2bf(v.y - bf2f(hi.y));
        lo.z = f2bf(v.z - bf2f(hi.z));
        lo.w = f2bf(v.w - bf2f(hi.w));
        ((ushort4*)(xl + o))[threadIdx.x] = lo;
    }
}

// W[mat] [1024][4096] f32 -> wh[mat][ug(64)][col(64)][k(1024)] bf16,
// col = gate*16 + a16 <-> global col gate*H + ug*16 + a16.
// lo for mats 0,2 at slot mat>>1.
__global__ __launch_bounds__(256) void k_warr(const float* __restrict__ w0,
                                              const float* __restrict__ w1,
                                              const float* __restrict__ w2,
                                              const float* __restrict__ w3,
                                              unsigned short* __restrict__ wh,
                                              unsigned short* __restrict__ wl,
                                              int use_lo) {
    int bid = blockIdx.x;               // 0..255
    int mat = bid >> 6, ug = bid & 63;
    const float* W = (mat == 0) ? w0 : (mat == 1) ? w1 : (mat == 2) ? w2 : w3;
    size_t dbase = ((size_t)(mat * NUG + ug) * 64) * Hh;
    size_t dlo   = ((size_t)(((mat >> 1) & 1) * NUG + ug) * 64) * Hh;
    const bool want_lo = use_lo && ((mat & 1) == 0);
    for (int it = 0; it < 256; ++it) {
        int idx = it * 256 + (int)threadIdx.x;
        int col = idx >> 10, k = idx & 1023;
        int cg = (col >> 4) * Hh + ug * 16 + (col & 15);
        float w = W[(size_t)k * 4096 + cg];
        unsigned short hi = f2bf(w);
        wh[dbase + (size_t)col * Hh + k] = hi;
        if (want_lo) wl[dlo + (size_t)col * Hh + k] = f2bf(w - bf2f(hi));
    }
}

template <bool USE_LO>
__global__ __launch_bounds__(512, 2) void k_lstm(
    const unsigned short* __restrict__ xTh,
    const unsigned short* __restrict__ xTl,
    const unsigned short* __restrict__ warrh,
    const unsigned short* __restrict__ warrl,
    unsigned int* __restrict__ hp0,        // [2][32][1024] u32 packed hi|lo<<16
    unsigned int* __restrict__ hp1,        // [2][32][1024] u32
    unsigned int* __restrict__ flags,      // [256] lines of 32 u32 (arrivals)
    unsigned int* __restrict__ ectr,       // [8] election ctr lines
    unsigned int* __restrict__ dflags,     // [8][32] lines (stage-done flags)
    unsigned int* __restrict__ pfl,        // [256] lines (exchange flags)
    float*        __restrict__ pex,        // [256][2][32][64] f32 partials
    unsigned short* __restrict__ hstage,   // [2][8][3][32][1024] bf16
    const float* __restrict__ b0,
    const float* __restrict__ b1,
    float* __restrict__ out)
{
    __shared__ float red[2][8][32][65];     // [layer][wave][row][col(+pad)]
    __shared__ float psum[2][32][65];       // reduced partials
    __shared__ unsigned hsh[2][32][4];      // packed h staging
    __shared__ int sRank;

    const int tid  = threadIdx.x;
    const int wave = tid >> 6;              // 0..7
    const int l    = tid & 63;
    const int wg   = blockIdx.x;
    const int q    = wg & 3;                // K-quarter
    const int qb   = wg & ~3;               // quad base
    const int ug   = wg >> 2;               // unit group (16 units)

    // ---- XCD identification + rank election (one-time RMW) ----
    unsigned xraw;
    asm volatile("s_getreg_b32 %0, hwreg(20, 0, 32)" : "=s"(xraw));  // HW_REG_XCC_ID [m09]
    const int xcd = (int)(xraw & 7u);
    if (tid == 0) sRank = (int)atomicAdd(&ectr[(size_t)xcd * 32], 1u);
    __syncthreads();
    const int rank = sRank;

    // K coverage: [q*256, +256); per wave 32, rotated per wg.
    const int kbase = q * 256 + ((wave + wg) & 7) * 32;

    // ---- persistent B fragments: [ch(4)] (one 32-K tile per wave) ----
    i32x4 Bih0h[4], Bhh0h[4], Bih1h[4], Bhh1h[4];
    i32x4 Bih0l[4], Bih1l[4];
    {
        const size_t matStride = (size_t)NUG * 64 * Hh;
        const size_t wgOff = (size_t)ug * 64 * Hh;
        #pragma unroll
        for (int ch = 0; ch < 4; ++ch) {
            size_t off = (size_t)(ch * 16 + (l & 15)) * Hh + kbase + ((l >> 4) * 8);
            Bih0h[ch] = pload_x4(warrh + 0 * matStride + wgOff + off);
            Bhh0h[ch] = pload_x4(warrh + 1 * matStride + wgOff + off);
            Bih1h[ch] = pload_x4(warrh + 2 * matStride + wgOff + off);
            Bhh1h[ch] = pload_x4(warrh + 3 * matStride + wgOff + off);
            if (USE_LO) {
                Bih0l[ch] = pload_x4(warrl + 0 * matStride + wgOff + off);
                Bih1l[ch] = pload_x4(warrl + 1 * matStride + wgOff + off);
            }
        }
        #pragma unroll
        for (int ch = 0; ch < 4; ++ch) {     // opacity: no remat
            asm volatile("" : "+v"(Bih0h[ch]), "+v"(Bhh0h[ch]),
                             "+v"(Bih1h[ch]), "+v"(Bhh1h[ch]));
            if (USE_LO)
                asm volatile("" : "+v"(Bih0l[ch]), "+v"(Bih1l[ch]));
        }
    }

    // ---- epilogue cell ownership (tid<256): <128 layer0, else layer1 ----
    const int cid = tid & 127;
    const int cb  = cid & 31;
    const int ca  = (cid >> 5) & 3;
    const int a16 = q * 4 + ca;         // unit within the 16-unit group
    const int cu  = wg * 4 + ca;        // global hidden unit (== ug*16+a16)
    const float* bias = (tid < 128) ? b0 : b1;
    const float bi  = bias[cu];
    const float bf_ = bias[Hh + cu];
    const float bg  = bias[2 * Hh + cu];
    const float bo  = bias[3 * Hh + cu];
    float c = 0.f;

    const int laneR = (l & 15);
    const int laneK = (l >> 4) * 8;

    f32x4 A0[2][4], A1[2][4];            // [m][ch]

    // x-projection terms (layer 0, h-independent) for step sidx -> A0
    auto xterms = [&](int sidx) {
        const unsigned short* xh = xTh + (size_t)sidx * (Bb * Hh);
        const unsigned short* xl = xTl + (size_t)sidx * (Bb * Hh);
        #pragma unroll
        for (int m = 0; m < 2; ++m) {
            const size_t off = (size_t)(m * 16 + laneR) * Hh + kbase + laneK;
            i32x4 axh = pload_x4(xh + off);
            i32x4 axl;
            if (USE_LO) axl = pload_x4(xl + off);
            #pragma unroll
            for (int ch = 0; ch < 4; ++ch) {
                mfma_bf16(A0[m][ch], axh, Bih0h[ch]);
                if (USE_LO) {
                    mfma_bf16(A0[m][ch], axh, Bih0l[ch]);
                    mfma_bf16(A0[m][ch], axl, Bih0h[ch]);
                }
            }
        }
    };

    #pragma unroll
    for (int m = 0; m < 2; ++m)
        #pragma unroll
        for (int ch = 0; ch < 4; ++ch) A0[m][ch] = f32x4{0,0,0,0};
    xterms(0);

    unsigned nx = 0, nx32 = 0;

    for (int s = 0; s <= Tt; ++s) {
        const int par_w = s & 1;
        const int par_r = par_w ^ 1;
        const size_t parWOff32 = (size_t)par_w * (Bb * Hh);
        const size_t parROff32 = (size_t)par_r * (Bb * Hh);
        const unsigned short* stb = hstage + ((size_t)(s & 1) * 8 + xcd) * ST3E;
        const unsigned tgt = (unsigned)(s + 1);

        #pragma unroll
        for (int m = 0; m < 2; ++m)
            #pragma unroll
            for (int ch = 0; ch < 4; ++ch) A1[m][ch] = f32x4{0,0,0,0};

        // ---- h-dependent MFMA terms from staged local-L2 copy (K-quarter) ----
        #pragma unroll
        for (int m = 0; m < 2; ++m) {
            const size_t off = (size_t)(m * 16 + laneR) * Hh + kbase + laneK;
            i32x4 g0h = pload_x4(stb + off);                 // h0 hi
            i32x4 g1h = pload_x4(stb + 2 * PLE + off);       // h1 hi
            i32x4 g0l;
            if (USE_LO) g0l = pload_x4(stb + PLE + off);     // h0 lo
            #pragma unroll
            for (int ch = 0; ch < 4; ++ch) {
                mfma_bf16(A0[m][ch], g0h, Bhh0h[ch]);   // h0*Whh0
                mfma_bf16(A1[m][ch], g0h, Bih1h[ch]);   // y0*Wih1
                mfma_bf16(A1[m][ch], g1h, Bhh1h[ch]);   // h1*Whh1
                if (USE_LO) {
                    mfma_bf16(A0[m][ch], g0l, Bhh0h[ch]);
                    mfma_bf16(A1[m][ch], g0h, Bih1l[ch]);
                    mfma_bf16(A1[m][ch], g0l, Bih1h[ch]);
                }
            }
        }
        asm("s_nop 7\n\ts_nop 7"
            : "+v"(A0[0][0]), "+v"(A0[0][1]), "+v"(A0[0][2]), "+v"(A0[0][3]),
              "+v"(A0[1][0]), "+v"(A0[1][1]), "+v"(A0[1][2]), "+v"(A0[1][3]),
              "+v"(A1[0][0]), "+v"(A1[0][1]), "+v"(A1[0][2]), "+v"(A1[0][3]),
              "+v"(A1[1][0]), "+v"(A1[1][1]), "+v"(A1[1][2]), "+v"(A1[1][3]));

        {
            const int r0 = (l >> 4) * 4;   // C/D: col=lane&15, row=(lane>>4)*4+reg [m89]
            const int cc = l & 15;
            #pragma unroll
            for (int m = 0; m < 2; ++m)
                #pragma unroll
                for (int ch = 0; ch < 4; ++ch)
                    #pragma unroll
                    for (int r = 0; r < 4; ++r) {
                        red[0][wave][m * 16 + r0 + r][ch * 16 + cc] = A0[m][ch][r];
                        red[1][wave][m * 16 + r0 + r][ch * 16 + cc] = A1[m][ch][r];
                    }
        }
        __syncthreads();

        // ---- 8-wave reduce -> psum (512 thr: ly, row, 8-col group) ----
        {
            const int ly = tid >> 8, u = tid & 255;
            const int rr = u >> 3, c8 = (u & 7) * 8;
            float p[8];
            #pragma unroll
            for (int j = 0; j < 8; ++j) p[j] = 0.f;
            #pragma unroll
            for (int w = 0; w < 8; ++w)
                #pragma unroll
                for (int j = 0; j < 8; ++j) p[j] += red[ly][w][rr][c8 + j];
            #pragma unroll
            for (int j = 0; j < 8; ++j) psum[ly][rr][c8 + j] = p[j];
        }
        __syncthreads();

        // ---- quad exchange: publish partials, poll 3 mates, add slices ----
        {
            const int ly = tid >> 8, u = tid & 255;
            const int rr = u >> 3, c8 = (u & 7) * 8;
            float* base = pex + (size_t)wg * 4096 + ((size_t)ly * 32 + rr) * 64 + c8;
            i32x4 v0, v1;
            v0[0] = __float_as_int(psum[ly][rr][c8]);
            v0[1] = __float_as_int(psum[ly][rr][c8 + 1]);
            v0[2] = __float_as_int(psum[ly][rr][c8 + 2]);
            v0[3] = __float_as_int(psum[ly][rr][c8 + 3]);
            v1[0] = __float_as_int(psum[ly][rr][c8 + 4]);
            v1[1] = __float_as_int(psum[ly][rr][c8 + 5]);
            v1[2] = __float_as_int(psum[ly][rr][c8 + 6]);
            v1[3] = __float_as_int(psum[ly][rr][c8 + 7]);
            ustore_x4(base, v0);
            ustore_x4(base + 4, v1);
            asm volatile("s_waitcnt vmcnt(0)" ::: "memory");
            __syncthreads();
            if (tid == 0) astore_u32(pfl + (size_t)wg * 32, tgt);
            int okp = 0;
            do {
                unsigned f = tgt;
                if (tid < 4 && tid != q)
                    f = aload_u32(pfl + (size_t)(qb + tid) * 32);
                okp = __syncthreads_and((int)(f >= tgt));
                if (!okp) __builtin_amdgcn_s_sleep(1);
            } while (!okp);
            if (tid < 256) {
                const int ly2 = tid >> 7, u2 = tid & 127;
                const int rr2 = u2 >> 2, g = u2 & 3;
                const int col = g * 16 + q * 4;
                #pragma unroll
                for (int pp = 0; pp < 4; ++pp) {
                    if (pp == q) continue;
                    i32x4 v = uload_x4(pex + (size_t)(qb + pp) * 4096
                                       + ((size_t)ly2 * 32 + rr2) * 64 + col);
                    psum[ly2][rr2][col]     += __int_as_float(v[0]);
                    psum[ly2][rr2][col + 1] += __int_as_float(v[1]);
                    psum[ly2][rr2][col + 2] += __int_as_float(v[2]);
                    psum[ly2][rr2][col + 3] += __int_as_float(v[3]);
                }
            }
            __syncthreads();
        }

        if (tid < 128) {                    // ---- layer 0 epilogue, t = s ----
            if (s < Tt) {
                float vi = bi  + psum[0][cb][a16];
                float vf = bf_ + psum[0][cb][16 + a16];
                float vg = bg  + psum[0][cb][32 + a16];
                float vo = bo  + psum[0][cb][48 + a16];
                float ig = sigm(vi), fg = sigm(vf), gg = tanh_f(vg), og = sigm(vo);
                c = fg * c + ig * gg;
                float h = og * tanh_f(c);
                unsigned short hh = f2bf(h);
                unsigned short hl = f2bf(h - bf2f(hh));
                hsh[0][cb][ca] = (unsigned)hh | ((unsigned)hl << 16);
                if (s == Tt - 1) {
                    out[16777216 + cb * Hh + cu] = h;          // h_n[0]
                    out[16777216 + 65536 + cb * Hh + cu] = c;  // c_n[0]
                }
            }
        } else if (tid < 256) {             // ---- layer 1 epilogue, t = s-1 ----
            if (s >= 1) {
                const int t = s - 1;
                float vi = bi  + psum[1][cb][a16];
                float vf = bf_ + psum[1][cb][16 + a16];
                float vg = bg  + psum[1][cb][32 + a16];
                float vo = bo  + psum[1][cb][48 + a16];
                float ig = sigm(vi), fg = sigm(vf), gg = tanh_f(vg), og = sigm(vo);
                c = fg * c + ig * gg;
                float h = og * tanh_f(c);
                unsigned short hh = f2bf(h);
                hsh[1][cb][ca] = (unsigned)hh;   // h1: hi only
                out[(size_t)cb * (Tt * Hh) + (size_t)t * Hh + cu] = h;   // y1
                if (s == Tt) {
                    out[16777216 + 32768 + cb * Hh + cu] = h;            // h_n[1]
                    out[16777216 + 65536 + 32768 + cb * Hh + cu] = c;    // c_n[1]
                }
            }
        }

        // ---- publish h (16B UC stores) + barrier + overlap + stage ----
        if (s < Tt) {
            __syncthreads();                 // hsh (LDS) visible to wave 0
            if (tid < 64) {                  // wave 0: gather + 16B UC stores
                const int buf = tid >> 5;
                const int cbb = tid & 31;
                if (buf == 0 || s >= 1) {
                    i32x4 hv;
                    hv[0] = (int)hsh[buf][cbb][0];
                    hv[1] = (int)hsh[buf][cbb][1];
                    hv[2] = (int)hsh[buf][cbb][2];
                    hv[3] = (int)hsh[buf][cbb][3];
                    unsigned int* dst = (buf ? (hp1 + parROff32) : (hp0 + parWOff32))
                                        + (size_t)cbb * Hh + wg * 4;
                    ustore_x4(dst, hv);
                }
            }
            asm volatile("s_waitcnt vmcnt(0)" ::: "memory");
            __syncthreads();
            if (tid == 0) astore_u32(flags + (size_t)wg * 32, tgt);  // arrival

            // overlap: next step's x-projection MFMAs (no h dependency)
            #pragma unroll
            for (int m = 0; m < 2; ++m)
                #pragma unroll
                for (int ch = 0; ch < 4; ++ch) A0[m][ch] = f32x4{0,0,0,0};
            xterms(s + 1);

            // symmetric arrival detect (r11-proven)
            int ok = 0;
            do {
                unsigned f = (tid < 256) ? aload_u32(flags + (size_t)tid * 32) : tgt;
                ok = __syncthreads_and((int)(f >= tgt));
                if (!ok) __builtin_amdgcn_s_sleep(2);
            } while (!ok);

            if (nx == 0) {
                nx = aload_u32(ectr + (size_t)xcd * 32);
                nx32 = nx < 32u ? nx : 32u;
            }

            // stage slices (r16-proven; full planes, all K)
            unsigned short* dstb = hstage + ((size_t)((s + 1) & 1) * 8 + xcd) * ST3E;
            for (int r = rank; r < 32; r += (int)nx) {
                const int buf = r >> 4;
                const unsigned int* sp = (buf == 0) ? (hp0 + parWOff32)
                                                    : (hp1 + parROff32);
                const int e = (r & 15) * 2048 + tid * 4;
                i32x4 v = uload_x4(sp + e);
                ushort4 hi4;
                hi4.x = (unsigned short)((unsigned)v[0] & 0xffffu);
                hi4.y = (unsigned short)((unsigned)v[1] & 0xffffu);
                hi4.z = (unsigned short)((unsigned)v[2] & 0xffffu);
                hi4.w = (unsigned short)((unsigned)v[3] & 0xffffu);
                unsigned short* dh = dstb + (buf == 0 ? 0 : 2 * PLE) + e;
                *(ushort4*)dh = hi4;
                if (buf == 0) {
                    ushort4 lo4;
                    lo4.x = (unsigned short)((unsigned)v[0] >> 16);
                    lo4.y = (unsigned short)((unsigned)v[1] >> 16);
                    lo4.z = (unsigned short)((unsigned)v[2] >> 16);
                    lo4.w = (unsigned short)((unsigned)v[3] >> 16);
                    *(ushort4*)(dstb + PLE + e) = lo4;
                }
            }
            asm volatile("s_waitcnt vmcnt(0)" ::: "memory");
            __syncthreads();
            if (tid == 0 && rank < 32)
                astore_u32(dflags + ((size_t)xcd * 32 + rank) * 32, tgt);
            int ok2 = 0;
            do {
                unsigned f = (tid < (int)nx32)
                    ? aload_u32(dflags + ((size_t)xcd * 32 + tid) * 32) : tgt;
                ok2 = __syncthreads_and((int)(f >= tgt));
                if (!ok2) __builtin_amdgcn_s_sleep(2);
            } while (!ok2);
        }
    }
}

extern "C" void kernel_launch(void* const* d_in, const int* in_sizes, int n_in,
                              void* d_out, int out_size, void* d_ws, size_t ws_size,
                              hipStream_t stream) {
    const float* x     = (const float*)d_in[0];
    const float* w_ih0 = (const float*)d_in[1];
    const float* w_hh0 = (const float*)d_in[2];
    const float* b0    = (const float*)d_in[3];
    const float* w_ih1 = (const float*)d_in[4];
    const float* w_hh1 = (const float*)d_in[5];
    const float* b1    = (const float*)d_in[6];
    float* out = (float*)d_out;

    const size_t SZ_WARRH = 33554432;   // 4*64*64*1024*2
    const size_t SZ_WARRL = 16777216;   // 2*64*64*1024*2
    const size_t SZ_XT    = 33619968;   // 513*32*1024*2
    const size_t SZ_HP    = 262144;     // [2][32][1024] u32, per buffer
    const size_t SZ_FLAGS = 32768;      // 256 lines x 128B
    const size_t SZ_ECTR  = 1024;
    const size_t SZ_DFLG  = 32768;
    const size_t SZ_PFL   = 32768;      // 256 lines x 128B (exchange flags)
    const size_t SZ_PEX   = 4194304;    // 256 x 16KB partial exchange
    const size_t SZ_STAGE = 3145728;    // 2*8*3*32*1024*2B

    char* ws = (char*)d_ws;
    unsigned short* warrh = (unsigned short*)ws;
    unsigned short* warrl = (unsigned short*)(ws + SZ_WARRH);
    unsigned short* xTh   = (unsigned short*)(ws + SZ_WARRH + SZ_WARRL);
    unsigned short* xTl   = (unsigned short*)(ws + SZ_WARRH + SZ_WARRL + SZ_XT);
    char* zbase = ws + SZ_WARRH + SZ_WARRL + 2 * SZ_XT;
    unsigned int* hp0    = (unsigned int*)zbase;
    unsigned int* hp1    = (unsigned int*)(zbase + SZ_HP);
    unsigned int* flags  = (unsigned int*)(zbase + 2 * SZ_HP);
    unsigned int* ectr   = (unsigned int*)(zbase + 2 * SZ_HP + SZ_FLAGS);
    unsigned int* dflags = (unsigned int*)(zbase + 2 * SZ_HP + SZ_FLAGS + SZ_ECTR);
    unsigned int* pfl    = (unsigned int*)(zbase + 2 * SZ_HP + SZ_FLAGS + SZ_ECTR + SZ_DFLG);
    float*        pex    = (float*)(zbase + 2 * SZ_HP + SZ_FLAGS + SZ_ECTR + SZ_DFLG + SZ_PFL);
    unsigned short* hstage =
        (unsigned short*)(zbase + 2 * SZ_HP + SZ_FLAGS + SZ_ECTR + SZ_DFLG + SZ_PFL + SZ_PEX);

    const size_t ZSZ  = 2 * SZ_HP + SZ_FLAGS + SZ_ECTR + SZ_DFLG + SZ_PFL + SZ_PEX + SZ_STAGE;
    const size_t FULL = SZ_WARRH + SZ_WARRL + 2 * SZ_XT + ZSZ;
    const bool use_lo = ws_size >= FULL;

    hipMemsetAsync(zbase, 0, ZSZ, stream);
    hipLaunchKernelGGL(k_xT,   dim3(16416), dim3(256), 0, stream, x, xTh, xTl, (int)use_lo);
    hipLaunchKernelGGL(k_warr, dim3(256),   dim3(256), 0, stream,
                       w_ih0, w_hh0, w_ih1, w_hh1, warrh, warrl, (int)use_lo);
    if (use_lo) {
        hipLaunchKernelGGL(k_lstm<true>, dim3(256), dim3(512), 0, stream,
                           xTh, xTl, warrh, warrl, hp0, hp1,
                           flags, ectr, dflags, pfl, pex, hstage, b0, b1, out);
    } else {
        hipLaunchKernelGGL(k_lstm<false>, dim3(256), dim3(512), 0, stream,
                           xTh, xTl, warrh, warrl, hp0, hp1,
                           flags, ectr, dflags, pfl, pex, hstage, b0, b1, out);
    }
}